// Round 7
// baseline (319.549 us; speedup 1.0000x reference)
//
#include <hip/hip_runtime.h>
#include <hip/hip_bf16.h>

typedef unsigned short u16;

#define BDIM 8
#define LDIM 8192
#define KDIM 256      // C
#define DDIM 256      // D
#define MTOT 65536    // B*L
#define NDIM 1536     // 6*D
#define TCH  32       // scan chunk length
#define NCH  256      // chunks per sequence

// Physical column layout of G (per m-row), dir f in {0,1}, base = f*768:
//   [base + 2d + 0] = h-gate col d   [base + 2d + 1] = z-gate col d  (d<256)
//   [base + 512 + d] = s-gate col d

typedef float floatx4 __attribute__((ext_vector_type(4)));
typedef short bf16x8 __attribute__((ext_vector_type(8)));

__device__ __forceinline__ u16 f2bf(float f) {
  union { __hip_bfloat16 h; u16 u; } c;
  c.h = __float2bfloat16(f);
  return c.u;
}
__device__ __forceinline__ float bf2f(u16 u) {
  union { unsigned int i; float f; } c;
  c.i = ((unsigned int)u) << 16;
  return c.f;
}
__device__ __forceinline__ float sigmoidf_fast(float x) {
  return __builtin_amdgcn_rcpf(1.0f + __expf(-x));
}
__device__ __forceinline__ void gll16(const u16* g, u16* l) {
  __builtin_amdgcn_global_load_lds((const __attribute__((address_space(1))) void*)g,
                                   (__attribute__((address_space(3))) void*)l, 16, 0, 0);
}

// ---------------------------------------------------------------------------
// Prep: WcatT[n][k] = W(n)[k][d(n)] bf16 with the interleaved physical layout.
// ---------------------------------------------------------------------------
__global__ void prep_weights(const float* __restrict__ Wh1, const float* __restrict__ Wz1,
                             const float* __restrict__ Ws1, const float* __restrict__ Wh_1,
                             const float* __restrict__ Wz_1, const float* __restrict__ Ws_1,
                             const float* __restrict__ bh1, const float* __restrict__ bz1,
                             const float* __restrict__ bs1, const float* __restrict__ bh_1,
                             const float* __restrict__ bz_1, const float* __restrict__ bs_1,
                             u16* __restrict__ WcatT, float* __restrict__ bcat) {
  const int n = blockIdx.x;       // physical col 0..1535
  const int k = threadIdx.x;      // 0..255
  const int dir = n / 768, r = n % 768;
  int d; const float* W; const float* bb;
  if (r < 512) {
    d = r >> 1;
    if (r & 1) { W = dir ? Wz_1 : Wz1; bb = dir ? bz_1 : bz1; }
    else       { W = dir ? Wh_1 : Wh1; bb = dir ? bh_1 : bh1; }
  } else {
    d = r - 512;
    W = dir ? Ws_1 : Ws1; bb = dir ? bs_1 : bs1;
  }
  WcatT[(size_t)n * KDIM + k] = f2bf(W[k * DDIM + d]);
  if (k == 0) bcat[n] = bb[d];
}

// ---------------------------------------------------------------------------
// Convert xs fp32 -> bf16
// ---------------------------------------------------------------------------
__global__ void convert_xs(const float* __restrict__ xs, u16* __restrict__ Abf) {
  size_t i = ((size_t)blockIdx.x * 256 + threadIdx.x) * 8;
  const float4* s = (const float4*)(xs + i);
  float4 f0 = s[0], f1 = s[1];
  union { u16 u[8]; uint4 v; } t;
  t.u[0] = f2bf(f0.x); t.u[1] = f2bf(f0.y); t.u[2] = f2bf(f0.z); t.u[3] = f2bf(f0.w);
  t.u[4] = f2bf(f1.x); t.u[5] = f2bf(f1.y); t.u[6] = f2bf(f1.z); t.u[7] = f2bf(f1.w);
  *(uint4*)(Abf + i) = t.v;
}

// ---------------------------------------------------------------------------
// GEMM + fused phaseA: 128x128 tile, BK=64, global_load_lds, XCD swizzle,
// XOR-swizzled LDS (verified conflict-free, R5). Epilogue on hz-tiles
// (nt 0..3 fwd / 6..9 bwd): round-trip the bf16 tile through LDS (stride 132
// pad -> conflict-free) and compute 32-t chunk affine summaries (Acc,Bcc).
// An m-tile is 128 consecutive t of one batch, so tile (mt,nt) holds h,z for
// 64 d x 128 t = 4 chunk summaries for d in [dbase, dbase+64).
// ---------------------------------------------------------------------------
__global__ __launch_bounds__(256) void gemm_kernel(const u16* __restrict__ Abf,
                                                   const u16* __restrict__ WcatT,
                                                   const float* __restrict__ bcat,
                                                   u16* __restrict__ G,
                                                   float* __restrict__ Acc,
                                                   float* __restrict__ Bcc) {
  __shared__ __align__(16) u16 smem[16896];   // As:8192 | Bs:8192 ; reused as 128x132 tile
  u16* As = smem;
  u16* Bs = smem + 8192;
  const int tid = threadIdx.x;
  const int lane = tid & 63, wave = tid >> 6;
  const int wm = wave >> 1, wn = wave & 1;
  const int q = lane >> 4, r = lane & 15;

  const int xcd = blockIdx.x & 7;
  const int li  = blockIdx.x >> 3;
  const int mt  = xcd * 64 + li / 12;
  const int nt  = li % 12;
  const int m0 = mt * 128, n0 = nt * 128;

  const u16* gA[4]; const u16* gB[4]; u16* lA[4]; u16* lB[4];
#pragma unroll
  for (int j = 0; j < 4; j++) {
    const int bi = wave * 256 + j * 64 + lane;   // LDS 16B-slot idx
    const int row = bi >> 3;
    const int kq = (bi & 7) ^ (row & 7);         // logical k-block for this slot
    gA[j] = Abf   + (size_t)(m0 + row) * KDIM + kq * 8;
    gB[j] = WcatT + (size_t)(n0 + row) * KDIM + kq * 8;
    lA[j] = As + bi * 8;
    lB[j] = Bs + bi * 8;
  }

  floatx4 acc[4][4];
  floatx4 z4 = {0.f, 0.f, 0.f, 0.f};
#pragma unroll
  for (int i = 0; i < 4; i++)
#pragma unroll
    for (int j = 0; j < 4; j++) acc[i][j] = z4;

  for (int k0 = 0; k0 < KDIM; k0 += 64) {
#pragma unroll
    for (int j = 0; j < 4; j++) { gll16(gA[j] + k0, lA[j]); gll16(gB[j] + k0, lB[j]); }
    __syncthreads();
#pragma unroll
    for (int kk = 0; kk < 2; kk++) {
      bf16x8 af[4], bv[4];
#pragma unroll
      for (int i = 0; i < 4; i++) {
        const int row = wm * 64 + i * 16 + r;
        af[i] = *(const bf16x8*)(As + (row * 8 + ((kk * 4 + q) ^ (row & 7))) * 8);
      }
#pragma unroll
      for (int j = 0; j < 4; j++) {
        const int row = wn * 64 + j * 16 + r;
        bv[j] = *(const bf16x8*)(Bs + (row * 8 + ((kk * 4 + q) ^ (row & 7))) * 8);
      }
#pragma unroll
      for (int i = 0; i < 4; i++)
#pragma unroll
        for (int j = 0; j < 4; j++)
          acc[i][j] = __builtin_amdgcn_mfma_f32_16x16x32_bf16(af[i], bv[j], acc[i][j], 0, 0, 0);
    }
    __syncthreads();
  }

  // ---- epilogue: G write + (hz tiles) LDS tile + chunk summaries ----
  // C/D layout: col = lane&15, row = (lane>>4)*4 + reg  [m89/m91]
  const bool is_hz = (nt < 4) | (nt >= 6 && nt < 10);
  float bvals[4];
#pragma unroll
  for (int j = 0; j < 4; j++) bvals[j] = bcat[n0 + wn * 64 + j * 16 + r];
#pragma unroll
  for (int i = 0; i < 4; i++) {
#pragma unroll
    for (int reg = 0; reg < 4; reg++) {
      const int row = wm * 64 + i * 16 + q * 4 + reg;
      u16* dst = G + (size_t)(m0 + row) * NDIM + n0 + wn * 64 + r;
#pragma unroll
      for (int j = 0; j < 4; j++) {
        const u16 v = f2bf(acc[i][j][reg] + bvals[j]);
        dst[j * 16] = v;
        if (is_hz) smem[row * 132 + wn * 64 + j * 16 + r] = v;
      }
    }
  }
  if (is_hz) {
    __syncthreads();
    const int dl = tid & 63, seg = tid >> 6;      // 64 d-lanes x 4 segments of 32 t
    const int dirn = (nt < 4) ? 0 : 1;
    const int dbase = (nt < 4) ? nt * 64 : (nt - 6) * 64;
    float h = 0.f, P = 1.f;
    if (dirn == 0) {
      for (int i = 0; i < 32; ++i) {
        const int t = seg * 32 + i;
        unsigned int hz32 = *(const unsigned int*)(smem + t * 132 + 2 * dl);
        float z = sigmoidf_fast(bf2f((u16)(hz32 >> 16)));
        float a = 1.f - z;
        h = fmaf(a, h, z * bf2f((u16)(hz32 & 0xffff)));
        P *= a;
      }
    } else {
      for (int i = 31; i >= 0; --i) {
        const int t = seg * 32 + i;
        unsigned int hz32 = *(const unsigned int*)(smem + t * 132 + 2 * dl);
        float z = sigmoidf_fast(bf2f((u16)(hz32 >> 16)));
        float a = 1.f - z;
        h = fmaf(a, h, z * bf2f((u16)(hz32 & 0xffff)));
        P *= a;
      }
    }
    const int b = m0 >> 13;                      // batch
    const int c = ((m0 & 8191) >> 5) + seg;      // 32-t chunk index
    const int u = dirn * 2048 + b * 256 + c;
    Acc[(size_t)u * 256 + dbase + dl] = P;
    Bcc[(size_t)u * 256 + dbase + dl] = h;
  }
}

// ---------------------------------------------------------------------------
// Scan phase B: chain 256 chunk summaries, 8-deep load batching.
// ---------------------------------------------------------------------------
__global__ void scan_phaseB(const float* __restrict__ Acc, const float* __restrict__ Bcc,
                            const float* __restrict__ h01, const float* __restrict__ h0_1,
                            float* __restrict__ Pref) {
  const int d = threadIdx.x, b = blockIdx.x, dir = blockIdx.y;
  float h = dir ? h0_1[d] : h01[d];
  const size_t ubase = ((size_t)dir * 2048 / NCH * NCH) + ((size_t)dir * 0);  // dummy
  const size_t base = ((size_t)dir * BDIM + b) * NCH;
  if (dir == 0) {
    for (int c0 = 0; c0 < NCH; c0 += 8) {
      float a[8], bb[8];
#pragma unroll
      for (int j = 0; j < 8; ++j) {
        size_t idx = (base + c0 + j) * DDIM + d;
        a[j] = Acc[idx]; bb[j] = Bcc[idx];
      }
#pragma unroll
      for (int j = 0; j < 8; ++j) {
        Pref[(base + c0 + j) * DDIM + d] = h;
        h = fmaf(a[j], h, bb[j]);
      }
    }
  } else {
    for (int c0 = NCH - 1; c0 >= 0; c0 -= 8) {
      float a[8], bb[8];
#pragma unroll
      for (int j = 0; j < 8; ++j) {
        size_t idx = (base + c0 - j) * DDIM + d;
        a[j] = Acc[idx]; bb[j] = Bcc[idx];
      }
#pragma unroll
      for (int j = 0; j < 8; ++j) {
        Pref[(base + c0 - j) * DDIM + d] = h;
        h = fmaf(a[j], h, bb[j]);
      }
    }
  }
}

// ---------------------------------------------------------------------------
// Scan phase C: block = one (b,c) chunk, 128 thr. Wave 0 = fwd chain,
// wave 1 = bwd chain, concurrent; 4 d/lane (uint4 hz = 1KB/wave loads);
// 4-deep explicit prefetch ring (loads are address-independent; only h is
// the serial dependency). Products stored bf16 in LDS; coalesced float4
// merge (chunk's out slice is flat-contiguous 32x256 floats).
// ---------------------------------------------------------------------------
__global__ __launch_bounds__(128) void scan_phaseC(const u16* __restrict__ G,
                                                   const float* __restrict__ Pref,
                                                   float* __restrict__ out) {
  __shared__ u16 fbuf[TCH * 256];   // 16 KB fwd products (bf16)
  __shared__ u16 bbuf[TCH * 256];   // 16 KB bwd products
  const int c = blockIdx.x & 255, b = blockIdx.x >> 8;
  const int dir = threadIdx.x >> 6, lane = threadIdx.x & 63;
  const int d0 = lane * 4;
  const int u = dir * 2048 + b * 256 + c;
  float4 hp = *(const float4*)(Pref + (size_t)u * 256 + d0);
  float h[4] = {hp.x, hp.y, hp.z, hp.w};
  const u16* ghz = G + (size_t)b * LDIM * NDIM + dir * 768 + d0 * 2;
  const u16* gs  = G + (size_t)b * LDIM * NDIM + dir * 768 + 512 + d0;
  u16* buf = dir ? bbuf : fbuf;
  const size_t tb = (size_t)c * TCH;

  uint4 hzb[4]; uint2 svb[4];
#pragma unroll
  for (int j = 0; j < 4; ++j) {
    const int tl = dir ? (TCH - 1 - j) : j;
    hzb[j] = *(const uint4*)(ghz + (tb + tl) * NDIM);
    svb[j] = *(const uint2*)(gs + (tb + tl) * NDIM);
  }
  for (int i0 = 0; i0 < TCH; i0 += 4) {
#pragma unroll
    for (int j = 0; j < 4; ++j) {
      const int i = i0 + j;
      const int tl = dir ? (TCH - 1 - i) : i;
      uint4 hz = hzb[j]; uint2 sv = svb[j];
      const int ip = i + 4;
      if (ip < TCH) {
        const int tlp = dir ? (TCH - 1 - ip) : ip;
        hzb[j] = *(const uint4*)(ghz + (tb + tlp) * NDIM);
        svb[j] = *(const uint2*)(gs + (tb + tlp) * NDIM);
      }
      const u16* q = (const u16*)&hz;
      const u16* sq = (const u16*)&sv;
#pragma unroll
      for (int e = 0; e < 4; ++e) {
        float z = sigmoidf_fast(bf2f(q[2 * e + 1]));
        h[e] = fmaf(1.f - z, h[e], z * bf2f(q[2 * e]));
      }
      uint2 pk;
      pk.x = (unsigned int)f2bf(h[0] * sigmoidf_fast(bf2f(sq[0])))
           | ((unsigned int)f2bf(h[1] * sigmoidf_fast(bf2f(sq[1]))) << 16);
      pk.y = (unsigned int)f2bf(h[2] * sigmoidf_fast(bf2f(sq[2])))
           | ((unsigned int)f2bf(h[3] * sigmoidf_fast(bf2f(sq[3]))) << 16);
      *(uint2*)(buf + tl * 256 + d0) = pk;
    }
  }
  __syncthreads();
  // Merge: out slice = 8192 contiguous floats. 128 thr x 4 elems x 16 iters.
  float* ob = out + ((size_t)b * LDIM + tb) * DDIM;
  for (int e = threadIdx.x * 4; e < TCH * 256; e += 128 * 4) {
    uint2 fv = *(const uint2*)(fbuf + e);
    uint2 bv = *(const uint2*)(bbuf + e);
    const u16* fq = (const u16*)&fv;
    const u16* bq = (const u16*)&bv;
    float4 o;
    o.x = bf2f(fq[0]) + bf2f(bq[0]);
    o.y = bf2f(fq[1]) + bf2f(bq[1]);
    o.z = bf2f(fq[2]) + bf2f(bq[2]);
    o.w = bf2f(fq[3]) + bf2f(bq[3]);
    *(float4*)(ob + e) = o;
  }
}

extern "C" void kernel_launch(void* const* d_in, const int* in_sizes, int n_in,
                              void* d_out, int out_size, void* d_ws, size_t ws_size,
                              hipStream_t stream) {
  const float* xs   = (const float*)d_in[0];
  const float* Wh1  = (const float*)d_in[1];
  const float* bh1  = (const float*)d_in[2];
  const float* Wz1  = (const float*)d_in[3];
  const float* bz1  = (const float*)d_in[4];
  const float* Ws1  = (const float*)d_in[5];
  const float* bs1  = (const float*)d_in[6];
  const float* h01  = (const float*)d_in[7];
  const float* Wh_1 = (const float*)d_in[8];
  const float* bh_1 = (const float*)d_in[9];
  const float* Wz_1 = (const float*)d_in[10];
  const float* bz_1 = (const float*)d_in[11];
  const float* Ws_1 = (const float*)d_in[12];
  const float* bs_1 = (const float*)d_in[13];
  const float* h0_1 = (const float*)d_in[14];
  float* out = (float*)d_out;

  char* ws = (char*)d_ws;
  u16* WcatT = (u16*)ws;    ws += (size_t)NDIM * KDIM * 2;           // 0.75 MB
  float* bcat = (float*)ws; ws += (size_t)NDIM * 4;                  // 6 KB
  u16* Abf = (u16*)ws;      ws += (size_t)MTOT * KDIM * 2;           // 32 MB
  u16* G = (u16*)ws;        ws += (size_t)MTOT * NDIM * 2;           // 192 MB
  float* Acc  = (float*)ws; ws += (size_t)2 * BDIM * NCH * DDIM * 4; // 4 MB
  float* Bcc  = (float*)ws; ws += (size_t)2 * BDIM * NCH * DDIM * 4; // 4 MB
  float* Pref = (float*)ws; ws += (size_t)2 * BDIM * NCH * DDIM * 4; // 4 MB
  if ((size_t)(ws - (char*)d_ws) > ws_size) return;

  prep_weights<<<dim3(NDIM), dim3(KDIM), 0, stream>>>(
      Wh1, Wz1, Ws1, Wh_1, Wz_1, Ws_1, bh1, bz1, bs1, bh_1, bz_1, bs_1, WcatT, bcat);
  convert_xs<<<dim3(MTOT * KDIM / (256 * 8)), dim3(256), 0, stream>>>(xs, Abf);
  gemm_kernel<<<dim3(6144), dim3(256), 0, stream>>>(Abf, WcatT, bcat, G, Acc, Bcc);
  scan_phaseB<<<dim3(BDIM, 2), dim3(DDIM), 0, stream>>>(Acc, Bcc, h01, h0_1, Pref);
  scan_phaseC<<<dim3(2048), dim3(128), 0, stream>>>(G, Pref, out);
}